// Round 1
// baseline (35.964 us; speedup 1.0000x reference)
//
#include <hip/hip_runtime.h>

// out[b,i,j,c] = sum_d tanh(start[b,c,i,d] + end[b,c,j,d]) * v[d]
// B=2, C=8, L=256, D=128.  Transcendental-bound: 1 exp2 + 1 rcp per (i,j,d).

#define LDIM 256
#define DDIM 128
#define TI 16
#define TJ 16
#define DPAD (DDIM + 4)   // 132 floats: breaks bank alignment, keeps 16B alignment

__global__ __launch_bounds__(256) void span_tanh_dot_kernel(
    const float* __restrict__ start_h,
    const float* __restrict__ end_h,
    const float* __restrict__ v,
    float* __restrict__ out,
    int C)
{
    __shared__ float s_t[TI][DPAD];
    __shared__ float e_t[TJ][DPAD];

    const int bc = blockIdx.z;            // b*C + c
    const int i0 = blockIdx.y * TI;
    const int j0 = blockIdx.x * TJ;
    const int tx = threadIdx.x;           // j within tile
    const int ty = threadIdx.y;           // i within tile
    const int tid = ty * TJ + tx;

    // scale by 2*log2(e) at staging so inner loop uses exp2 directly:
    // tanh(x) = 1 - 2 / (e^{2x} + 1),  e^{2x} = exp2(K*x)
    const float K = 2.8853900817779268f;

    const float* sg = start_h + ((size_t)bc * LDIM + i0) * DDIM;
    const float* eg = end_h   + ((size_t)bc * LDIM + j0) * DDIM;

    // stage 16x128 s-tile and e-tile, pre-scaled. 512 float4 chunks per tile,
    // 256 threads -> 2 chunks each per tile. Coalesced global reads.
    #pragma unroll
    for (int idx = tid; idx < TI * (DDIM / 4); idx += 256) {
        const int r  = idx >> 5;
        const int c4 = (idx & 31) << 2;
        float4 a = *(const float4*)(sg + r * DDIM + c4);
        a.x *= K; a.y *= K; a.z *= K; a.w *= K;
        *(float4*)(&s_t[r][c4]) = a;
        float4 b = *(const float4*)(eg + r * DDIM + c4);
        b.x *= K; b.y *= K; b.z *= K; b.w *= K;
        *(float4*)(&e_t[r][c4]) = b;
    }
    __syncthreads();

    const float* srow = &s_t[ty][0];
    const float* erow = &e_t[tx][0];

    float acc = 0.0f;
    #pragma unroll 8
    for (int d = 0; d < DDIM; d += 4) {
        float4 sv = *(const float4*)(srow + d);   // ds_read_b128, broadcast over tx
        float4 ev = *(const float4*)(erow + d);   // ds_read_b128, 2-way max (free)
        float4 wv = *(const float4*)(v + d);      // wave-uniform -> s_load_dwordx4

        float x0 = sv.x + ev.x;
        float x1 = sv.y + ev.y;
        float x2 = sv.z + ev.z;
        float x3 = sv.w + ev.w;

        float r0 = __builtin_amdgcn_rcpf(__builtin_amdgcn_exp2f(x0) + 1.0f);
        float r1 = __builtin_amdgcn_rcpf(__builtin_amdgcn_exp2f(x1) + 1.0f);
        float r2 = __builtin_amdgcn_rcpf(__builtin_amdgcn_exp2f(x2) + 1.0f);
        float r3 = __builtin_amdgcn_rcpf(__builtin_amdgcn_exp2f(x3) + 1.0f);

        float t0 = fmaf(-2.0f, r0, 1.0f);
        float t1 = fmaf(-2.0f, r1, 1.0f);
        float t2 = fmaf(-2.0f, r2, 1.0f);
        float t3 = fmaf(-2.0f, r3, 1.0f);

        acc = fmaf(t0, wv.x, acc);
        acc = fmaf(t1, wv.y, acc);
        acc = fmaf(t2, wv.z, acc);
        acc = fmaf(t3, wv.w, acc);
    }

    const int b = bc / C;
    const int c = bc - b * C;
    const int i = i0 + ty;
    const int j = j0 + tx;
    // out shape [B, L, L, C]
    out[(((size_t)b * LDIM + i) * LDIM + j) * C + c] = acc;
}

extern "C" void kernel_launch(void* const* d_in, const int* in_sizes, int n_in,
                              void* d_out, int out_size, void* d_ws, size_t ws_size,
                              hipStream_t stream) {
    const float* start_h = (const float*)d_in[0];
    const float* end_h   = (const float*)d_in[1];
    const float* v       = (const float*)d_in[2];
    float* out = (float*)d_out;

    const int BC = in_sizes[0] / (LDIM * DDIM);  // B*C = 16
    const int C  = 8;

    dim3 grid(LDIM / TJ, LDIM / TI, BC);   // (16,16,16)
    dim3 block(TJ, TI);                    // 256 threads
    span_tanh_dot_kernel<<<grid, block, 0, stream>>>(start_h, end_h, v, out, C);
}

// Round 2
// 21.096 us; speedup vs baseline: 1.7048x; 1.7048x over previous
//
#include <hip/hip_runtime.h>

// out[b,i,j,c] = sum_d tanh(start[b,c,i,d] + end[b,c,j,d]) * v[d]
// B=2, C=8, L=256, D=128.
//
// Key identity: tanh(x) = 1 - 2/(e^{2x}+1), and e^{2(s+e)} = Es*Ee with
// Es=exp2(K*s), Ee=exp2(K*e), K=2*log2(e).  So the 134M-element inner loop
// has NO exp — only mul, add, rcp.  rcp is merged over d-pairs:
//   v0/a + v1/b = (v0*b + v1*a) / (a*b)   -> 0.5 rcp per element.
// out = sum(v) - 2 * sum_d v_d/(p_d+1).

#define LDIM 256
#define DDIM 128
#define DPAD 132   // 33 x 16B quads per row (odd) -> conflict-free strided rows

__device__ __forceinline__ float quad_term(const float4 s, const float4 e,
                                           float v0, float v1, float v2, float v3) {
    // returns sum over 4 consecutive d of v_d / (Es*Ee + 1)
    float p0 = s.x * e.x, p1 = s.y * e.y, p2 = s.z * e.z, p3 = s.w * e.w;
    float a = p0 + 1.0f, b = p1 + 1.0f, c = p2 + 1.0f, d = p3 + 1.0f;
    float n01 = fmaf(v1, a, v0 * b);
    float n23 = fmaf(v3, c, v2 * d);
    float r01 = __builtin_amdgcn_rcpf(a * b);
    float r23 = __builtin_amdgcn_rcpf(c * d);
    return fmaf(n01, r01, n23 * r23);
}

__global__ __launch_bounds__(256) void span_tanh_dot_kernel(
    const float* __restrict__ start_h,
    const float* __restrict__ end_h,
    const float* __restrict__ v,
    float* __restrict__ out,
    int C)
{
    __shared__ float s_t[32][DPAD];
    __shared__ float e_t[32][DPAD];
    __shared__ float s_vsum;

    const int bc = blockIdx.z;            // b*C + c
    const int i0 = blockIdx.y * 32;
    const int j0 = blockIdx.x * 32;
    const int tx = threadIdx.x;           // 0..15 (j)
    const int ty = threadIdx.y;           // 0..15 (i)
    const int tid = ty * 16 + tx;

    const float K = 2.8853900817779268f;  // 2*log2(e)

    const float* sg = start_h + ((size_t)bc * LDIM + i0) * DDIM;
    const float* eg = end_h   + ((size_t)bc * LDIM + j0) * DDIM;

    // stage 32x128 tiles of Es=exp2(K*s), Ee=exp2(K*e). 1024 float4 per tensor,
    // 4 per thread. Coalesced global reads; staging exps are negligible (32/thread).
    #pragma unroll
    for (int idx = tid; idx < 32 * 32; idx += 256) {
        const int r  = idx >> 5;
        const int c4 = (idx & 31) << 2;
        float4 a = *(const float4*)(sg + r * DDIM + c4);
        a.x = __builtin_amdgcn_exp2f(K * a.x);
        a.y = __builtin_amdgcn_exp2f(K * a.y);
        a.z = __builtin_amdgcn_exp2f(K * a.z);
        a.w = __builtin_amdgcn_exp2f(K * a.w);
        *(float4*)(&s_t[r][c4]) = a;
        float4 b = *(const float4*)(eg + r * DDIM + c4);
        b.x = __builtin_amdgcn_exp2f(K * b.x);
        b.y = __builtin_amdgcn_exp2f(K * b.y);
        b.z = __builtin_amdgcn_exp2f(K * b.z);
        b.w = __builtin_amdgcn_exp2f(K * b.w);
        *(float4*)(&e_t[r][c4]) = b;
    }

    // sum(v) once per block: wave 0 reduces 128 floats
    if (tid < 64) {
        float2 vv = *(const float2*)(v + 2 * tid);
        float p = vv.x + vv.y;
        #pragma unroll
        for (int off = 32; off > 0; off >>= 1) p += __shfl_down(p, off);
        if (tid == 0) s_vsum = p;
    }
    __syncthreads();

    // 2x2 register blocking, strided: rows {ty, ty+16} x cols {tx, tx+16}
    const float* s0 = &s_t[ty][0];
    const float* s1 = &s_t[ty + 16][0];
    const float* e0 = &e_t[tx][0];
    const float* e1 = &e_t[tx + 16][0];

    float acc00 = 0.f, acc01 = 0.f, acc10 = 0.f, acc11 = 0.f;

    #pragma unroll 4
    for (int d = 0; d < DDIM; d += 4) {
        const float4 sa = *(const float4*)(s0 + d);  // broadcast across tx
        const float4 sb = *(const float4*)(s1 + d);
        const float4 ea = *(const float4*)(e0 + d);  // 16 rows, odd-quad stride: free
        const float4 eb = *(const float4*)(e1 + d);
        const float v0 = v[d], v1 = v[d + 1], v2 = v[d + 2], v3 = v[d + 3];

        acc00 += quad_term(sa, ea, v0, v1, v2, v3);
        acc01 += quad_term(sa, eb, v0, v1, v2, v3);
        acc10 += quad_term(sb, ea, v0, v1, v2, v3);
        acc11 += quad_term(sb, eb, v0, v1, v2, v3);
    }

    const int b = bc / C;
    const int c = bc - b * C;
    const float S = s_vsum;
    const int ia = i0 + ty, ib = i0 + ty + 16;
    const int ja = j0 + tx, jb = j0 + tx + 16;
    const size_t base = ((size_t)b * LDIM) * LDIM * C + c;

    out[base + ((size_t)ia * LDIM + ja) * C] = fmaf(-2.f, acc00, S);
    out[base + ((size_t)ia * LDIM + jb) * C] = fmaf(-2.f, acc01, S);
    out[base + ((size_t)ib * LDIM + ja) * C] = fmaf(-2.f, acc10, S);
    out[base + ((size_t)ib * LDIM + jb) * C] = fmaf(-2.f, acc11, S);
}

extern "C" void kernel_launch(void* const* d_in, const int* in_sizes, int n_in,
                              void* d_out, int out_size, void* d_ws, size_t ws_size,
                              hipStream_t stream) {
    const float* start_h = (const float*)d_in[0];
    const float* end_h   = (const float*)d_in[1];
    const float* v       = (const float*)d_in[2];
    float* out = (float*)d_out;

    const int BC = in_sizes[0] / (LDIM * DDIM);  // B*C = 16
    const int C  = 8;

    dim3 grid(LDIM / 32, LDIM / 32, BC);   // (8, 8, 16) = 1024 blocks
    dim3 block(16, 16);                    // 256 threads, 4 waves
    span_tanh_dot_kernel<<<grid, block, 0, stream>>>(start_h, end_h, v, out, C);
}